// Round 4
// baseline (222.169 us; speedup 1.0000x reference)
//
#include <hip/hip_runtime.h>

// Causal SDPA, B=16, N=4096, DK=DV=64, fp32 in/out. R13 = R12 with the
// one-line correctness fix: V B-fragment granule index was missing the wk
// half-offset (wk*4), so wk=1 waves multiplied P(kpos 32..63) by V(kpos
// 0..31) -> absmax 1.21. Now granule = (wk*4 + t*2 + h) ^ l7.
// R12 design (carried): all MFMAs 32x32x16 (wave quadrant = 32q x 32kpos =
// ONE 32x32 output):
//  - QK: 4x mfma_f32_32x32x16_bf16, PV: 4, ones-rowsum: 2. 28 -> 10 MFMAs
//    per wave-ktile.
//  - K-image rows permuted by swapping bits 2<->3 of the row index: QK
//    C-layout reg order then EQUALS the PV A-layout k order; P->A is just
//    the 8 cvt_pk. Mask kpos = K0[rr]+8h, K0[rr]=(rr&7)|((rr&8)<<1).
//  - V image in 16B granules (granule c^(dv&7) of row dv = kpos octet c):
//    PV B-frags are single ds_read_b128.
// Carried: exact static split-K schedule (32/33 k-tiles/worker, no atomics),
// global_load_lds width=16 double-buffered, 2x2 wave split (wq,wk) with
// cross-wk LDS reduction, P=exp2 static softmax, 4 blocks/CU (32 KB LDS).

#define N_SEQ 4096
#define DIM   64

typedef __bf16  bf16x8 __attribute__((ext_vector_type(8)));
typedef unsigned short u16x8 __attribute__((ext_vector_type(8)));
typedef float   f32x4  __attribute__((ext_vector_type(4)));
typedef float   f32x16 __attribute__((ext_vector_type(16)));

static __device__ __forceinline__ unsigned short f2bf(float f) {
    unsigned int u = __float_as_uint(f);
    u += 0x7FFFu + ((u >> 16) & 1u);   // RNE
    return (unsigned short)(u >> 16);
}

static __device__ __forceinline__ unsigned int pk2bf(float a, float b) {
#if defined(__HIP_DEVICE_COMPILE__) && __has_builtin(__builtin_amdgcn_cvt_pk_bf16_f32)
    typedef __bf16 bf16x2_t __attribute__((ext_vector_type(2)));
    bf16x2_t r = __builtin_amdgcn_cvt_pk_bf16_f32(a, b);
    return __builtin_bit_cast(unsigned int, r);
#else
    return (unsigned int)f2bf(a) | ((unsigned int)f2bf(b) << 16);
#endif
}

static __device__ __forceinline__ float fexp2(float x) {
#if defined(__HIP_DEVICE_COMPILE__) && __has_builtin(__builtin_amdgcn_exp2f)
    return __builtin_amdgcn_exp2f(x);
#else
    return exp2f(x);
#endif
}

static __device__ __forceinline__ bf16x8 ld_frag(const void* p) {
    u16x8 u = *reinterpret_cast<const u16x8*>(p);  // ds_read_b128
    return __builtin_bit_cast(bf16x8, u);
}

// 32x32x16 bf16 MFMA: A,B = 8 bf16/lane (4 VGPR), C/D = 16 f32/lane.
static __device__ __forceinline__ f32x16 mfma32(bf16x8 a, bf16x8 b, f32x16 c) {
#if defined(__HIP_DEVICE_COMPILE__)
#if __has_builtin(__builtin_amdgcn_mfma_f32_32x32x16_bf16)
    return __builtin_amdgcn_mfma_f32_32x32x16_bf16(a, b, c, 0, 0, 0);
#else
    f32x16 d;
    asm volatile("v_mfma_f32_32x32x16_bf16 %0, %1, %2, %3"
                 : "=v"(d) : "v"(a), "v"(b), "v"(c));
    return d;
#endif
#else
    (void)a; (void)b;
    return c;
#endif
}

static __device__ __forceinline__ void gl_lds16(const unsigned short* g, unsigned short* l) {
#if defined(__HIP_DEVICE_COMPILE__)
    __builtin_amdgcn_global_load_lds(
        (const __attribute__((address_space(1))) unsigned int*)(g),
        (__attribute__((address_space(3))) unsigned int*)(l), 16, 0, 0);
#else
    (void)g; (void)l;
#endif
}

// ---- fused pre-pass: z=0: K image (rows bit2<->3 permuted); z=1: V^T image ----
__global__ __launch_bounds__(256)
void prep_kv(const float* __restrict__ K, const float* __restrict__ V,
             unsigned short* __restrict__ wsK, unsigned short* __restrict__ wsV) {
    const int b = blockIdx.y, t = blockIdx.x;
    if (blockIdx.z == 0) {
        const float* src = K + ((size_t)b * N_SEQ + t * 64) * DIM;
        unsigned short* dst = wsK + ((size_t)(b * 64 + t)) * 4096;
        #pragma unroll
        for (int ph = 0; ph < 2; ++ph) {
            const int gidx = threadIdx.x + ph * 256;
            const int r = gidx >> 3, g = gidx & 7;     // r = actual kpos, g = dk octet
            const float* p = src + r * DIM + g * 8;
            f32x4 f0 = *reinterpret_cast<const f32x4*>(p);
            f32x4 f1 = *reinterpret_cast<const f32x4*>(p + 4);
            uint4 w;
            w.x = pk2bf(f0[0], f0[1]); w.y = pk2bf(f0[2], f0[3]);
            w.z = pk2bf(f1[0], f1[1]); w.w = pk2bf(f1[2], f1[3]);
            // image row = r with bits 2,3 swapped (involution)
            const int rp = (r & 51) | ((r & 4) << 1) | ((r & 8) >> 1);
            *reinterpret_cast<uint4*>(&dst[(rp * 8 + (g ^ (rp & 7))) * 8]) = w;
        }
    } else {
        // V^T image: row dv (64 kpos bf16 = 128 B = 8 granules of 8 bf16).
        // Granule (c ^ (dv&7)) of row dv holds kpos octet c*8..c*8+7.
        const int dv = threadIdx.x & 63;
        const int g0 = threadIdx.x >> 6;               // 0..3
        const float* src = V + ((size_t)b * N_SEQ + t * 64) * DIM + dv;
        unsigned short* dst = wsV + ((size_t)(b * 64 + t)) * 4096 + dv * 64;
        #pragma unroll
        for (int ph = 0; ph < 2; ++ph) {
            const int c = g0 * 2 + ph;                 // content octet 0..7
            float p[8];
            #pragma unroll
            for (int e = 0; e < 8; ++e)
                p[e] = src[(size_t)(c * 8 + e) * DIM]; // coalesced over dv
            uint4 w;
            w.x = pk2bf(p[0], p[1]); w.y = pk2bf(p[2], p[3]);
            w.z = pk2bf(p[4], p[5]); w.w = pk2bf(p[6], p[7]);
            *reinterpret_cast<uint4*>(&dst[(c ^ (dv & 7)) * 8]) = w;
        }
    }
}

// ---- main: flash attention, static split-K schedule, 32x32 MFMAs ----
__global__ __launch_bounds__(256, 4)
void attn_fwd(const float* __restrict__ Q, const unsigned short* __restrict__ wsK,
              const unsigned short* __restrict__ wsV, float* __restrict__ O,
              float* __restrict__ wsO, float* __restrict__ wsL) {
    __shared__ unsigned short kbuf[2][4096];   // 8 KB each
    __shared__ unsigned short vbuf[2][4096];

    const int tid  = threadIdx.x;
    const int wave = tid >> 6;
    const int lane = tid & 63;
    const int l31  = lane & 31;
    const int h    = lane >> 5;        // half-wave
    const int l7   = lane & 7;
    const int wq   = wave & 1;         // q-half     (rows wq*32..+32 of the tile)
    const int wk   = wave >> 1;        // kpos-half  (kpos wk*32..+32 of the k-tile)

    const int L    = (int)blockIdx.x;
    const int r    = L & 7;            // XCD queue (batches {2r,2r+1})
    const int w    = L >> 3;           // worker 0..127
    const int role = w & 1;            // 0=A, 1=B
    const int bsel = (w >> 1) & 1;
    const int j    = w >> 2;           // pair index 0..31
    const int b    = r * 2 + bsel;
    const int T    = 63 - j;           // deep tile of the pair (depth 64-j)

    // item list (<=2): {tile, kt0, kt1, partial(half)}
    int it_tile[2], it_k0[2], it_k1[2], it_half[2], n_items;
    if (role == 0) {                   // A: tile j full + head of T
        it_tile[0] = j;  it_k0[0] = 0; it_k1[0] = j + 1;  it_half[0] = -1;
        it_tile[1] = T;  it_k0[1] = 0; it_k1[1] = 31 - j; it_half[1] = 0;
        n_items = 2;                   // total (j+1)+(31-j) = 32
    } else {                           // B: tail of T (33 k-tiles)
        it_tile[0] = T;  it_k0[0] = 31 - j; it_k1[0] = 64 - j; it_half[0] = 1;
        n_items = 1;
    }

    // loop-invariant LDS byte addresses
    int kaddr[4];   // [s]: K A-frag, image row wk*32+l31, granule (s*2+h)^l7
    #pragma unroll
    for (int s = 0; s < 4; ++s)
        kaddr[s] = (wk * 32 + l31) * 128 + (((s * 2 + h) ^ l7) * 16);
    int vbase[2];   // [t]: V B-frag, row l31 (+dvt*32 via imm), granule (wk*4+t*2+h)^l7
    #pragma unroll
    for (int t = 0; t < 2; ++t)
        vbase[t] = l31 * 128 + (((wk * 4 + t * 2 + h) ^ l7) * 16);

    const int dma_off = wave * 1024 + lane * 8;       // u16; 16B per lane
    const u16x8 ones_u = {0x3F80, 0x3F80, 0x3F80, 0x3F80,
                          0x3F80, 0x3F80, 0x3F80, 0x3F80};
    const bf16x8 ones8 = __builtin_bit_cast(bf16x8, ones_u);
    const float QS = 0.125f * 1.44269504f;            // scale * log2(e)

    const unsigned short* kt_src = wsK + (size_t)b * 64 * 4096;
    const unsigned short* vt_src = wsV + (size_t)b * 64 * 4096;

    for (int it = 0; it < n_items; ++it) {
        const int tt   = it_tile[it];
        const int kt0  = it_k0[it];
        const int kt1  = it_k1[it];
        const int half = it_half[it];
        const int i0   = tt * 64;

        __syncthreads();                 // LDS free from previous item

        f32x16 o_acc[2] = {};  // [dvt]: D[q][dv], col dv=dvt*32+l31, rows q-pattern
        f32x16 lones = {};     // row sums via ones-MFMA (same q rows, every lane)

        if (kt0 < kt1) {
            // Q fragments (B-operand): lane = q row wq*32+l31, k = s*16+h*8+j
            u16x8 qb[4];
            const float* qptr = Q + ((size_t)b * N_SEQ + i0 + wq * 32 + l31) * DIM;
            #pragma unroll
            for (int s = 0; s < 4; ++s) {
                const float* p = qptr + s * 16 + h * 8;
                f32x4 f0 = *reinterpret_cast<const f32x4*>(p);
                f32x4 f1 = *reinterpret_cast<const f32x4*>(p + 4);
                #pragma unroll
                for (int jj = 0; jj < 4; ++jj) {
                    qb[s][jj]     = f2bf(f0[jj] * QS);
                    qb[s][4 + jj] = f2bf(f1[jj] * QS);
                }
            }

            auto dma = [&](int kt, int bufi) {            // 16 KB per k-tile
                const unsigned short* ks = kt_src + (size_t)kt * 4096 + dma_off;
                const unsigned short* vs = vt_src + (size_t)kt * 4096 + dma_off;
                #pragma unroll
                for (int i = 0; i < 2; ++i) {
                    gl_lds16(ks + i * 512, &kbuf[bufi][wave * 1024 + i * 512]);
                    gl_lds16(vs + i * 512, &vbuf[bufi][wave * 1024 + i * 512]);
                }
            };

            auto compute = [&](int kt, const unsigned short* kb, const unsigned short* vb) {
                // S^T quadrant = K(wk-half, row-permuted) * Q^T(wq-half)
                // D: col = q = l31, reg rr = kpos K0[rr]+8h (image perm folded)
                f32x16 st = {};
                #pragma unroll
                for (int s = 0; s < 4; ++s) {
                    bf16x8 kf = ld_frag((const char*)kb + kaddr[s]);
                    st = mfma32(kf, __builtin_bit_cast(bf16x8, qb[s]), st);
                }
                // P = exp2(S^T) (+ causal mask on diagonal tile)
                float pex[16];
                if (kt == tt) {
                    const int qth = wq * 32 + l31 - 8 * h - wk * 32;
                    #pragma unroll
                    for (int rr = 0; rr < 16; ++rr) {
                        const int K0 = (rr & 7) | ((rr & 8) << 1);
                        pex[rr] = fexp2((K0 > qth) ? -3.0e38f : st[rr]);
                    }
                } else {
                    #pragma unroll
                    for (int rr = 0; rr < 16; ++rr)
                        pex[rr] = fexp2(st[rr]);
                }
                // reg order == PV A-layout k order (thanks to K row permutation):
                // A slice t = words u[4t..4t+3], kpos = wk*32 + 16t + 8h + (0..7)
                unsigned int u[8];
                #pragma unroll
                for (int g = 0; g < 4; ++g) {
                    u[2 * g]     = pk2bf(pex[4 * g],     pex[4 * g + 1]);
                    u[2 * g + 1] = pk2bf(pex[4 * g + 2], pex[4 * g + 3]);
                }
                // O += P V ; l += P * ones
                #pragma unroll
                for (int t = 0; t < 2; ++t) {
                    uint4 aw = make_uint4(u[4 * t], u[4 * t + 1], u[4 * t + 2], u[4 * t + 3]);
                    bf16x8 pa = __builtin_bit_cast(bf16x8, aw);
                    #pragma unroll
                    for (int dvt = 0; dvt < 2; ++dvt) {
                        bf16x8 bv = ld_frag((const char*)vb + vbase[t] + dvt * 4096);
                        o_acc[dvt] = mfma32(pa, bv, o_acc[dvt]);
                    }
                    lones = mfma32(pa, ones8, lones);
                }
            };

            dma(kt0, 0);
            int kt = kt0, bufi = 0;
            while (true) {
                __syncthreads();                   // drains own DMA + aligns waves
                if (kt + 1 < kt1) dma(kt + 1, bufi ^ 1);
                compute(kt, kbuf[bufi], vbuf[bufi]);
                if (++kt == kt1) break;
                bufi ^= 1;
            }
        }

        // ---- cross-wk reduction through the freed k-tile LDS (once per item) ----
        __syncthreads();                           // everyone done with kbuf/vbuf
        float* red  = reinterpret_cast<float*>(&kbuf[0][0]);   // 4096 f32 = 16 KB
        float* lred = reinterpret_cast<float*>(&vbuf[0][0]);   // 64 f32 used
        if (wk == 1) {
            #pragma unroll
            for (int rr = 0; rr < 16; ++rr) {
                const int qrow = (rr & 3) + 8 * (rr >> 2) + 4 * h;
                #pragma unroll
                for (int dvt = 0; dvt < 2; ++dvt)
                    red[wq * 2048 + qrow * 64 + dvt * 32 + l31] = o_acc[dvt][rr];
                if (l31 == 0) lred[wq * 32 + qrow] = lones[rr];
            }
        }
        __syncthreads();
        if (wk == 0) {
            if (half < 0) {
                // final: normalize and write O directly
                float* obase = O + ((size_t)b * N_SEQ + i0 + wq * 32) * DIM;
                #pragma unroll
                for (int rr = 0; rr < 16; ++rr) {
                    const int qrow = (rr & 3) + 8 * (rr >> 2) + 4 * h;
                    const float lt = lones[rr] + lred[wq * 32 + qrow];
                    const float inv = 1.0f / lt;
                    #pragma unroll
                    for (int dvt = 0; dvt < 2; ++dvt) {
                        const float val = o_acc[dvt][rr]
                            + red[wq * 2048 + qrow * 64 + dvt * 32 + l31];
                        obase[qrow * DIM + dvt * 32 + l31] = val * inv;
                    }
                }
            } else {
                // raw additive partial -> workspace (zeros if empty range)
                float* po = wsO + (((size_t)(b * 32 + (tt - 32)) * 2 + half) * 4096);
                float* pl = wsL + (((size_t)(b * 32 + (tt - 32)) * 2 + half) * 64);
                #pragma unroll
                for (int rr = 0; rr < 16; ++rr) {
                    const int qrow = (rr & 3) + 8 * (rr >> 2) + 4 * h;
                    const float lt = lones[rr] + lred[wq * 32 + qrow];
                    #pragma unroll
                    for (int dvt = 0; dvt < 2; ++dvt)
                        po[(wq * 32 + qrow) * 64 + dvt * 32 + l31] = o_acc[dvt][rr]
                            + red[wq * 2048 + qrow * 64 + dvt * 32 + l31];
                    if (l31 == 0) pl[wq * 32 + qrow] = lt;
                }
            }
        }
        // next item's top-of-loop __syncthreads() protects kbuf/vbuf reuse
    }
}

// ---- combine split-K partials for tiles 32..63 ----
__global__ __launch_bounds__(256)
void norm_out(const float* __restrict__ wsO, const float* __restrict__ wsL,
              float* __restrict__ O) {
    const int t = 32 + blockIdx.x, b = blockIdx.y;
    const int row = threadIdx.x >> 2;            // 0..63
    const int c0  = (threadIdx.x & 3) * 16;      // 0,16,32,48
    const size_t base = (size_t)(b * 32 + (t - 32)) * 2;
    const float* p0 = wsO + base * 4096 + row * 64 + c0;
    const float* p1 = p0 + 4096;
    const float* l  = wsL + base * 64;
    const float inv = 1.0f / (l[row] + l[64 + row]);
    float* o = O + ((size_t)b * N_SEQ + t * 64 + row) * 64 + c0;
    #pragma unroll
    for (int i = 0; i < 16; i += 4) {
        f32x4 a = *reinterpret_cast<const f32x4*>(p0 + i);
        f32x4 c = *reinterpret_cast<const f32x4*>(p1 + i);
        f32x4 v = (a + c) * inv;
        *reinterpret_cast<f32x4*>(o + i) = v;
    }
}

extern "C" void kernel_launch(void* const* d_in, const int* in_sizes, int n_in,
                              void* d_out, int out_size, void* d_ws, size_t ws_size,
                              hipStream_t stream) {
    const float* q = (const float*)d_in[0];
    const float* k = (const float*)d_in[1];
    const float* v = (const float*)d_in[2];
    // d_in[3] = causal mask, analytic (tril) -- not read.
    float* out = (float*)d_out;

    unsigned short* wsK = (unsigned short*)d_ws;
    unsigned short* wsV = wsK + (size_t)16 * 64 * 4096;        // 8 MB each
    float* wsO = (float*)(wsV + (size_t)16 * 64 * 4096);       // 16.8 MB
    float* wsL = wsO + (size_t)16 * 32 * 2 * 4096;             // 0.26 MB

    prep_kv<<<dim3(64, 16, 2), dim3(256), 0, stream>>>(k, v, wsK, wsV);
    attn_fwd<<<dim3(1024), dim3(256), 0, stream>>>(q, wsK, wsV, out, wsO, wsL);
    norm_out<<<dim3(32, 16), dim3(256), 0, stream>>>(wsO, wsL, out);
}

// Round 5
// 206.613 us; speedup vs baseline: 1.0753x; 1.0753x over previous
//
#include <hip/hip_runtime.h>

// Causal SDPA, B=16, N=4096, DK=DV=64, fp32 in/out. R14 = R13 with ONE change:
// __launch_bounds__(256, 2) on attn_fwd (was (256, 4)). R13 post-mortem:
// (256,4) pinned the allocator to 64 VGPRs while the 32x32-MFMA design's
// persistent state alone (o_acc 32 + lones 16 + qb 16) is 64 -> hot-loop
// scratch spill (+88 MB WRITE_SIZE, +23 MB FETCH_SIZE, MfmaUtil 33->17.5,
// dur 71.6->100 us). With min-waves=2 the VGPR cap is >=128; pressure ~115
// fits, and <=128 VGPRs still yields 4 waves/SIMD = 4 blocks/CU.
// R13 design (carried, correctness-verified absmax 0.0156):
//  - all MFMAs 32x32x16 (wave quadrant = 32q x 32kpos = ONE 32x32 output):
//    QK 4x, PV 4x, ones-rowsum 2x = 10 MFMAs/wave-ktile (was 28 in R11).
//  - K-image rows permuted (bits 2<->3 swapped): QK C-layout reg order ==
//    PV A-layout k order; P->A is just 8 cvt_pk. Mask kpos = K0[rr]+8h,
//    K0[rr]=(rr&7)|((rr&8)<<1).
//  - V image in 16B granules (granule c^(dv&7) of row dv = kpos octet c):
//    PV B-frags are single ds_read_b128; granule idx (wk*4+t*2+h)^l7.
// Carried: exact static split-K schedule (32/33 k-tiles/worker, no atomics),
// global_load_lds width=16 double-buffered, 2x2 wave split (wq,wk) with
// cross-wk LDS reduction, P=exp2 static softmax, 32 KB LDS/block.

#define N_SEQ 4096
#define DIM   64

typedef __bf16  bf16x8 __attribute__((ext_vector_type(8)));
typedef unsigned short u16x8 __attribute__((ext_vector_type(8)));
typedef float   f32x4  __attribute__((ext_vector_type(4)));
typedef float   f32x16 __attribute__((ext_vector_type(16)));

static __device__ __forceinline__ unsigned short f2bf(float f) {
    unsigned int u = __float_as_uint(f);
    u += 0x7FFFu + ((u >> 16) & 1u);   // RNE
    return (unsigned short)(u >> 16);
}

static __device__ __forceinline__ unsigned int pk2bf(float a, float b) {
#if defined(__HIP_DEVICE_COMPILE__) && __has_builtin(__builtin_amdgcn_cvt_pk_bf16_f32)
    typedef __bf16 bf16x2_t __attribute__((ext_vector_type(2)));
    bf16x2_t r = __builtin_amdgcn_cvt_pk_bf16_f32(a, b);
    return __builtin_bit_cast(unsigned int, r);
#else
    return (unsigned int)f2bf(a) | ((unsigned int)f2bf(b) << 16);
#endif
}

static __device__ __forceinline__ float fexp2(float x) {
#if defined(__HIP_DEVICE_COMPILE__) && __has_builtin(__builtin_amdgcn_exp2f)
    return __builtin_amdgcn_exp2f(x);
#else
    return exp2f(x);
#endif
}

static __device__ __forceinline__ bf16x8 ld_frag(const void* p) {
    u16x8 u = *reinterpret_cast<const u16x8*>(p);  // ds_read_b128
    return __builtin_bit_cast(bf16x8, u);
}

// 32x32x16 bf16 MFMA: A,B = 8 bf16/lane (4 VGPR), C/D = 16 f32/lane.
static __device__ __forceinline__ f32x16 mfma32(bf16x8 a, bf16x8 b, f32x16 c) {
#if defined(__HIP_DEVICE_COMPILE__)
#if __has_builtin(__builtin_amdgcn_mfma_f32_32x32x16_bf16)
    return __builtin_amdgcn_mfma_f32_32x32x16_bf16(a, b, c, 0, 0, 0);
#else
    f32x16 d;
    asm volatile("v_mfma_f32_32x32x16_bf16 %0, %1, %2, %3"
                 : "=v"(d) : "v"(a), "v"(b), "v"(c));
    return d;
#endif
#else
    (void)a; (void)b;
    return c;
#endif
}

static __device__ __forceinline__ void gl_lds16(const unsigned short* g, unsigned short* l) {
#if defined(__HIP_DEVICE_COMPILE__)
    __builtin_amdgcn_global_load_lds(
        (const __attribute__((address_space(1))) unsigned int*)(g),
        (__attribute__((address_space(3))) unsigned int*)(l), 16, 0, 0);
#else
    (void)g; (void)l;
#endif
}

// ---- fused pre-pass: z=0: K image (rows bit2<->3 permuted); z=1: V^T image ----
__global__ __launch_bounds__(256)
void prep_kv(const float* __restrict__ K, const float* __restrict__ V,
             unsigned short* __restrict__ wsK, unsigned short* __restrict__ wsV) {
    const int b = blockIdx.y, t = blockIdx.x;
    if (blockIdx.z == 0) {
        const float* src = K + ((size_t)b * N_SEQ + t * 64) * DIM;
        unsigned short* dst = wsK + ((size_t)(b * 64 + t)) * 4096;
        #pragma unroll
        for (int ph = 0; ph < 2; ++ph) {
            const int gidx = threadIdx.x + ph * 256;
            const int r = gidx >> 3, g = gidx & 7;     // r = actual kpos, g = dk octet
            const float* p = src + r * DIM + g * 8;
            f32x4 f0 = *reinterpret_cast<const f32x4*>(p);
            f32x4 f1 = *reinterpret_cast<const f32x4*>(p + 4);
            uint4 w;
            w.x = pk2bf(f0[0], f0[1]); w.y = pk2bf(f0[2], f0[3]);
            w.z = pk2bf(f1[0], f1[1]); w.w = pk2bf(f1[2], f1[3]);
            // image row = r with bits 2,3 swapped (involution)
            const int rp = (r & 51) | ((r & 4) << 1) | ((r & 8) >> 1);
            *reinterpret_cast<uint4*>(&dst[(rp * 8 + (g ^ (rp & 7))) * 8]) = w;
        }
    } else {
        // V^T image: row dv (64 kpos bf16 = 128 B = 8 granules of 8 bf16).
        // Granule (c ^ (dv&7)) of row dv holds kpos octet c*8..c*8+7.
        const int dv = threadIdx.x & 63;
        const int g0 = threadIdx.x >> 6;               // 0..3
        const float* src = V + ((size_t)b * N_SEQ + t * 64) * DIM + dv;
        unsigned short* dst = wsV + ((size_t)(b * 64 + t)) * 4096 + dv * 64;
        #pragma unroll
        for (int ph = 0; ph < 2; ++ph) {
            const int c = g0 * 2 + ph;                 // content octet 0..7
            float p[8];
            #pragma unroll
            for (int e = 0; e < 8; ++e)
                p[e] = src[(size_t)(c * 8 + e) * DIM]; // coalesced over dv
            uint4 w;
            w.x = pk2bf(p[0], p[1]); w.y = pk2bf(p[2], p[3]);
            w.z = pk2bf(p[4], p[5]); w.w = pk2bf(p[6], p[7]);
            *reinterpret_cast<uint4*>(&dst[(c ^ (dv & 7)) * 8]) = w;
        }
    }
}

// ---- main: flash attention, static split-K schedule, 32x32 MFMAs ----
__global__ __launch_bounds__(256, 2)
void attn_fwd(const float* __restrict__ Q, const unsigned short* __restrict__ wsK,
              const unsigned short* __restrict__ wsV, float* __restrict__ O,
              float* __restrict__ wsO, float* __restrict__ wsL) {
    __shared__ unsigned short kbuf[2][4096];   // 8 KB each
    __shared__ unsigned short vbuf[2][4096];

    const int tid  = threadIdx.x;
    const int wave = tid >> 6;
    const int lane = tid & 63;
    const int l31  = lane & 31;
    const int h    = lane >> 5;        // half-wave
    const int l7   = lane & 7;
    const int wq   = wave & 1;         // q-half     (rows wq*32..+32 of the tile)
    const int wk   = wave >> 1;        // kpos-half  (kpos wk*32..+32 of the k-tile)

    const int L    = (int)blockIdx.x;
    const int r    = L & 7;            // XCD queue (batches {2r,2r+1})
    const int w    = L >> 3;           // worker 0..127
    const int role = w & 1;            // 0=A, 1=B
    const int bsel = (w >> 1) & 1;
    const int j    = w >> 2;           // pair index 0..31
    const int b    = r * 2 + bsel;
    const int T    = 63 - j;           // deep tile of the pair (depth 64-j)

    // item list (<=2): {tile, kt0, kt1, partial(half)}
    int it_tile[2], it_k0[2], it_k1[2], it_half[2], n_items;
    if (role == 0) {                   // A: tile j full + head of T
        it_tile[0] = j;  it_k0[0] = 0; it_k1[0] = j + 1;  it_half[0] = -1;
        it_tile[1] = T;  it_k0[1] = 0; it_k1[1] = 31 - j; it_half[1] = 0;
        n_items = 2;                   // total (j+1)+(31-j) = 32
    } else {                           // B: tail of T (33 k-tiles)
        it_tile[0] = T;  it_k0[0] = 31 - j; it_k1[0] = 64 - j; it_half[0] = 1;
        n_items = 1;
    }

    // loop-invariant LDS byte addresses
    int kaddr[4];   // [s]: K A-frag, image row wk*32+l31, granule (s*2+h)^l7
    #pragma unroll
    for (int s = 0; s < 4; ++s)
        kaddr[s] = (wk * 32 + l31) * 128 + (((s * 2 + h) ^ l7) * 16);
    int vbase[2];   // [t]: V B-frag, row l31 (+dvt*32 via imm), granule (wk*4+t*2+h)^l7
    #pragma unroll
    for (int t = 0; t < 2; ++t)
        vbase[t] = l31 * 128 + (((wk * 4 + t * 2 + h) ^ l7) * 16);

    const int dma_off = wave * 1024 + lane * 8;       // u16; 16B per lane
    const u16x8 ones_u = {0x3F80, 0x3F80, 0x3F80, 0x3F80,
                          0x3F80, 0x3F80, 0x3F80, 0x3F80};
    const bf16x8 ones8 = __builtin_bit_cast(bf16x8, ones_u);
    const float QS = 0.125f * 1.44269504f;            // scale * log2(e)

    const unsigned short* kt_src = wsK + (size_t)b * 64 * 4096;
    const unsigned short* vt_src = wsV + (size_t)b * 64 * 4096;

    for (int it = 0; it < n_items; ++it) {
        const int tt   = it_tile[it];
        const int kt0  = it_k0[it];
        const int kt1  = it_k1[it];
        const int half = it_half[it];
        const int i0   = tt * 64;

        __syncthreads();                 // LDS free from previous item

        f32x16 o_acc[2] = {};  // [dvt]: D[q][dv], col dv=dvt*32+l31, rows q-pattern
        f32x16 lones = {};     // row sums via ones-MFMA (same q rows, every lane)

        if (kt0 < kt1) {
            // Q fragments (B-operand): lane = q row wq*32+l31, k = s*16+h*8+j
            u16x8 qb[4];
            const float* qptr = Q + ((size_t)b * N_SEQ + i0 + wq * 32 + l31) * DIM;
            #pragma unroll
            for (int s = 0; s < 4; ++s) {
                const float* p = qptr + s * 16 + h * 8;
                f32x4 f0 = *reinterpret_cast<const f32x4*>(p);
                f32x4 f1 = *reinterpret_cast<const f32x4*>(p + 4);
                #pragma unroll
                for (int jj = 0; jj < 4; ++jj) {
                    qb[s][jj]     = f2bf(f0[jj] * QS);
                    qb[s][4 + jj] = f2bf(f1[jj] * QS);
                }
            }

            auto dma = [&](int kt, int bufi) {            // 16 KB per k-tile
                const unsigned short* ks = kt_src + (size_t)kt * 4096 + dma_off;
                const unsigned short* vs = vt_src + (size_t)kt * 4096 + dma_off;
                #pragma unroll
                for (int i = 0; i < 2; ++i) {
                    gl_lds16(ks + i * 512, &kbuf[bufi][wave * 1024 + i * 512]);
                    gl_lds16(vs + i * 512, &vbuf[bufi][wave * 1024 + i * 512]);
                }
            };

            auto compute = [&](int kt, const unsigned short* kb, const unsigned short* vb) {
                // S^T quadrant = K(wk-half, row-permuted) * Q^T(wq-half)
                // D: col = q = l31, reg rr = kpos K0[rr]+8h (image perm folded)
                f32x16 st = {};
                #pragma unroll
                for (int s = 0; s < 4; ++s) {
                    bf16x8 kf = ld_frag((const char*)kb + kaddr[s]);
                    st = mfma32(kf, __builtin_bit_cast(bf16x8, qb[s]), st);
                }
                // P = exp2(S^T) (+ causal mask on diagonal tile)
                float pex[16];
                if (kt == tt) {
                    const int qth = wq * 32 + l31 - 8 * h - wk * 32;
                    #pragma unroll
                    for (int rr = 0; rr < 16; ++rr) {
                        const int K0 = (rr & 7) | ((rr & 8) << 1);
                        pex[rr] = fexp2((K0 > qth) ? -3.0e38f : st[rr]);
                    }
                } else {
                    #pragma unroll
                    for (int rr = 0; rr < 16; ++rr)
                        pex[rr] = fexp2(st[rr]);
                }
                // reg order == PV A-layout k order (thanks to K row permutation):
                // A slice t = words u[4t..4t+3], kpos = wk*32 + 16t + 8h + (0..7)
                unsigned int u[8];
                #pragma unroll
                for (int g = 0; g < 4; ++g) {
                    u[2 * g]     = pk2bf(pex[4 * g],     pex[4 * g + 1]);
                    u[2 * g + 1] = pk2bf(pex[4 * g + 2], pex[4 * g + 3]);
                }
                // O += P V ; l += P * ones
                #pragma unroll
                for (int t = 0; t < 2; ++t) {
                    uint4 aw = make_uint4(u[4 * t], u[4 * t + 1], u[4 * t + 2], u[4 * t + 3]);
                    bf16x8 pa = __builtin_bit_cast(bf16x8, aw);
                    #pragma unroll
                    for (int dvt = 0; dvt < 2; ++dvt) {
                        bf16x8 bv = ld_frag((const char*)vb + vbase[t] + dvt * 4096);
                        o_acc[dvt] = mfma32(pa, bv, o_acc[dvt]);
                    }
                    lones = mfma32(pa, ones8, lones);
                }
            };

            dma(kt0, 0);
            int kt = kt0, bufi = 0;
            while (true) {
                __syncthreads();                   // drains own DMA + aligns waves
                if (kt + 1 < kt1) dma(kt + 1, bufi ^ 1);
                compute(kt, kbuf[bufi], vbuf[bufi]);
                if (++kt == kt1) break;
                bufi ^= 1;
            }
        }

        // ---- cross-wk reduction through the freed k-tile LDS (once per item) ----
        __syncthreads();                           // everyone done with kbuf/vbuf
        float* red  = reinterpret_cast<float*>(&kbuf[0][0]);   // 4096 f32 = 16 KB
        float* lred = reinterpret_cast<float*>(&vbuf[0][0]);   // 64 f32 used
        if (wk == 1) {
            #pragma unroll
            for (int rr = 0; rr < 16; ++rr) {
                const int qrow = (rr & 3) + 8 * (rr >> 2) + 4 * h;
                #pragma unroll
                for (int dvt = 0; dvt < 2; ++dvt)
                    red[wq * 2048 + qrow * 64 + dvt * 32 + l31] = o_acc[dvt][rr];
                if (l31 == 0) lred[wq * 32 + qrow] = lones[rr];
            }
        }
        __syncthreads();
        if (wk == 0) {
            if (half < 0) {
                // final: normalize and write O directly
                float* obase = O + ((size_t)b * N_SEQ + i0 + wq * 32) * DIM;
                #pragma unroll
                for (int rr = 0; rr < 16; ++rr) {
                    const int qrow = (rr & 3) + 8 * (rr >> 2) + 4 * h;
                    const float lt = lones[rr] + lred[wq * 32 + qrow];
                    const float inv = 1.0f / lt;
                    #pragma unroll
                    for (int dvt = 0; dvt < 2; ++dvt) {
                        const float val = o_acc[dvt][rr]
                            + red[wq * 2048 + qrow * 64 + dvt * 32 + l31];
                        obase[qrow * DIM + dvt * 32 + l31] = val * inv;
                    }
                }
            } else {
                // raw additive partial -> workspace (zeros if empty range)
                float* po = wsO + (((size_t)(b * 32 + (tt - 32)) * 2 + half) * 4096);
                float* pl = wsL + (((size_t)(b * 32 + (tt - 32)) * 2 + half) * 64);
                #pragma unroll
                for (int rr = 0; rr < 16; ++rr) {
                    const int qrow = (rr & 3) + 8 * (rr >> 2) + 4 * h;
                    const float lt = lones[rr] + lred[wq * 32 + qrow];
                    #pragma unroll
                    for (int dvt = 0; dvt < 2; ++dvt)
                        po[(wq * 32 + qrow) * 64 + dvt * 32 + l31] = o_acc[dvt][rr]
                            + red[wq * 2048 + qrow * 64 + dvt * 32 + l31];
                    if (l31 == 0) pl[wq * 32 + qrow] = lt;
                }
            }
        }
        // next item's top-of-loop __syncthreads() protects kbuf/vbuf reuse
    }
}

// ---- combine split-K partials for tiles 32..63 ----
__global__ __launch_bounds__(256)
void norm_out(const float* __restrict__ wsO, const float* __restrict__ wsL,
              float* __restrict__ O) {
    const int t = 32 + blockIdx.x, b = blockIdx.y;
    const int row = threadIdx.x >> 2;            // 0..63
    const int c0  = (threadIdx.x & 3) * 16;      // 0,16,32,48
    const size_t base = (size_t)(b * 32 + (t - 32)) * 2;
    const float* p0 = wsO + base * 4096 + row * 64 + c0;
    const float* p1 = p0 + 4096;
    const float* l  = wsL + base * 64;
    const float inv = 1.0f / (l[row] + l[64 + row]);
    float* o = O + ((size_t)b * N_SEQ + t * 64 + row) * 64 + c0;
    #pragma unroll
    for (int i = 0; i < 16; i += 4) {
        f32x4 a = *reinterpret_cast<const f32x4*>(p0 + i);
        f32x4 c = *reinterpret_cast<const f32x4*>(p1 + i);
        f32x4 v = (a + c) * inv;
        *reinterpret_cast<f32x4*>(o + i) = v;
    }
}

extern "C" void kernel_launch(void* const* d_in, const int* in_sizes, int n_in,
                              void* d_out, int out_size, void* d_ws, size_t ws_size,
                              hipStream_t stream) {
    const float* q = (const float*)d_in[0];
    const float* k = (const float*)d_in[1];
    const float* v = (const float*)d_in[2];
    // d_in[3] = causal mask, analytic (tril) -- not read.
    float* out = (float*)d_out;

    unsigned short* wsK = (unsigned short*)d_ws;
    unsigned short* wsV = wsK + (size_t)16 * 64 * 4096;        // 8 MB each
    float* wsO = (float*)(wsV + (size_t)16 * 64 * 4096);       // 16.8 MB
    float* wsL = wsO + (size_t)16 * 32 * 2 * 4096;             // 0.26 MB

    prep_kv<<<dim3(64, 16, 2), dim3(256), 0, stream>>>(k, v, wsK, wsV);
    attn_fwd<<<dim3(1024), dim3(256), 0, stream>>>(q, wsK, wsV, out, wsO, wsL);
    norm_out<<<dim3(32, 16), dim3(256), 0, stream>>>(wsO, wsL, out);
}

// Round 6
// 206.024 us; speedup vs baseline: 1.0784x; 1.0029x over previous
//
#include <hip/hip_runtime.h>

// Causal SDPA, B=16, N=4096, DK=DV=64, fp32 in/out. R15 = R14 with ONE change:
// the k-loop's __syncthreads() (which compiles to s_waitcnt vmcnt(0) +
// s_barrier, draining the prefetch every tile) is replaced by the counted-
// vmcnt two-barrier pipeline:
//   s_barrier                  (buf^1 free: all waves done reading it)
//   dma(kt+1 -> buf^1)         (4 global_load_lds, stay in flight)
//   s_waitcnt vmcnt(4)         (wait only kt's loads -- issued 1 iter ago)
//   s_barrier                  (kt staged data visible to all waves)
//   compute(kt)
// R14 post-mortem: MFMA/VALU time dropped exactly as predicted (17.6/29.8 us)
// but the vmcnt(0) barrier drain grew ~+20 us once compute shrank below DMA
// latency. This removes the drain (never vmcnt(0) in the main loop).
// Carried from R14/R13: all MFMAs 32x32x16 (QK 4, PV 4, ones 2 = 10/wave-
// ktile); K-image rows bit2<->3 permuted so QK C-reg order == PV A-k order
// (P->A = 8 cvt_pk); V image 16B granules (c^(dv&7)); launch_bounds(256,2)
// (VGPR ~116, no spill); exact static split-K schedule; 2x2 wave split with
// cross-wk LDS reduction; P=exp2 static softmax; 32 KB LDS/block.

#define N_SEQ 4096
#define DIM   64

typedef __bf16  bf16x8 __attribute__((ext_vector_type(8)));
typedef unsigned short u16x8 __attribute__((ext_vector_type(8)));
typedef float   f32x4  __attribute__((ext_vector_type(4)));
typedef float   f32x16 __attribute__((ext_vector_type(16)));

static __device__ __forceinline__ unsigned short f2bf(float f) {
    unsigned int u = __float_as_uint(f);
    u += 0x7FFFu + ((u >> 16) & 1u);   // RNE
    return (unsigned short)(u >> 16);
}

static __device__ __forceinline__ unsigned int pk2bf(float a, float b) {
#if defined(__HIP_DEVICE_COMPILE__) && __has_builtin(__builtin_amdgcn_cvt_pk_bf16_f32)
    typedef __bf16 bf16x2_t __attribute__((ext_vector_type(2)));
    bf16x2_t r = __builtin_amdgcn_cvt_pk_bf16_f32(a, b);
    return __builtin_bit_cast(unsigned int, r);
#else
    return (unsigned int)f2bf(a) | ((unsigned int)f2bf(b) << 16);
#endif
}

static __device__ __forceinline__ float fexp2(float x) {
#if defined(__HIP_DEVICE_COMPILE__) && __has_builtin(__builtin_amdgcn_exp2f)
    return __builtin_amdgcn_exp2f(x);
#else
    return exp2f(x);
#endif
}

static __device__ __forceinline__ bf16x8 ld_frag(const void* p) {
    u16x8 u = *reinterpret_cast<const u16x8*>(p);  // ds_read_b128
    return __builtin_bit_cast(bf16x8, u);
}

// 32x32x16 bf16 MFMA: A,B = 8 bf16/lane (4 VGPR), C/D = 16 f32/lane.
static __device__ __forceinline__ f32x16 mfma32(bf16x8 a, bf16x8 b, f32x16 c) {
#if defined(__HIP_DEVICE_COMPILE__)
#if __has_builtin(__builtin_amdgcn_mfma_f32_32x32x16_bf16)
    return __builtin_amdgcn_mfma_f32_32x32x16_bf16(a, b, c, 0, 0, 0);
#else
    f32x16 d;
    asm volatile("v_mfma_f32_32x32x16_bf16 %0, %1, %2, %3"
                 : "=v"(d) : "v"(a), "v"(b), "v"(c));
    return d;
#endif
#else
    (void)a; (void)b;
    return c;
#endif
}

static __device__ __forceinline__ void gl_lds16(const unsigned short* g, unsigned short* l) {
#if defined(__HIP_DEVICE_COMPILE__)
    __builtin_amdgcn_global_load_lds(
        (const __attribute__((address_space(1))) unsigned int*)(g),
        (__attribute__((address_space(3))) unsigned int*)(l), 16, 0, 0);
#else
    (void)g; (void)l;
#endif
}

// ---- fused pre-pass: z=0: K image (rows bit2<->3 permuted); z=1: V^T image ----
__global__ __launch_bounds__(256)
void prep_kv(const float* __restrict__ K, const float* __restrict__ V,
             unsigned short* __restrict__ wsK, unsigned short* __restrict__ wsV) {
    const int b = blockIdx.y, t = blockIdx.x;
    if (blockIdx.z == 0) {
        const float* src = K + ((size_t)b * N_SEQ + t * 64) * DIM;
        unsigned short* dst = wsK + ((size_t)(b * 64 + t)) * 4096;
        #pragma unroll
        for (int ph = 0; ph < 2; ++ph) {
            const int gidx = threadIdx.x + ph * 256;
            const int r = gidx >> 3, g = gidx & 7;     // r = actual kpos, g = dk octet
            const float* p = src + r * DIM + g * 8;
            f32x4 f0 = *reinterpret_cast<const f32x4*>(p);
            f32x4 f1 = *reinterpret_cast<const f32x4*>(p + 4);
            uint4 w;
            w.x = pk2bf(f0[0], f0[1]); w.y = pk2bf(f0[2], f0[3]);
            w.z = pk2bf(f1[0], f1[1]); w.w = pk2bf(f1[2], f1[3]);
            // image row = r with bits 2,3 swapped (involution)
            const int rp = (r & 51) | ((r & 4) << 1) | ((r & 8) >> 1);
            *reinterpret_cast<uint4*>(&dst[(rp * 8 + (g ^ (rp & 7))) * 8]) = w;
        }
    } else {
        // V^T image: row dv (64 kpos bf16 = 128 B = 8 granules of 8 bf16).
        // Granule (c ^ (dv&7)) of row dv holds kpos octet c*8..c*8+7.
        const int dv = threadIdx.x & 63;
        const int g0 = threadIdx.x >> 6;               // 0..3
        const float* src = V + ((size_t)b * N_SEQ + t * 64) * DIM + dv;
        unsigned short* dst = wsV + ((size_t)(b * 64 + t)) * 4096 + dv * 64;
        #pragma unroll
        for (int ph = 0; ph < 2; ++ph) {
            const int c = g0 * 2 + ph;                 // content octet 0..7
            float p[8];
            #pragma unroll
            for (int e = 0; e < 8; ++e)
                p[e] = src[(size_t)(c * 8 + e) * DIM]; // coalesced over dv
            uint4 w;
            w.x = pk2bf(p[0], p[1]); w.y = pk2bf(p[2], p[3]);
            w.z = pk2bf(p[4], p[5]); w.w = pk2bf(p[6], p[7]);
            *reinterpret_cast<uint4*>(&dst[(c ^ (dv & 7)) * 8]) = w;
        }
    }
}

// ---- main: flash attention, static split-K schedule, 32x32 MFMAs ----
__global__ __launch_bounds__(256, 2)
void attn_fwd(const float* __restrict__ Q, const unsigned short* __restrict__ wsK,
              const unsigned short* __restrict__ wsV, float* __restrict__ O,
              float* __restrict__ wsO, float* __restrict__ wsL) {
    __shared__ unsigned short kbuf[2][4096];   // 8 KB each
    __shared__ unsigned short vbuf[2][4096];

    const int tid  = threadIdx.x;
    const int wave = tid >> 6;
    const int lane = tid & 63;
    const int l31  = lane & 31;
    const int h    = lane >> 5;        // half-wave
    const int l7   = lane & 7;
    const int wq   = wave & 1;         // q-half     (rows wq*32..+32 of the tile)
    const int wk   = wave >> 1;        // kpos-half  (kpos wk*32..+32 of the k-tile)

    const int L    = (int)blockIdx.x;
    const int r    = L & 7;            // XCD queue (batches {2r,2r+1})
    const int w    = L >> 3;           // worker 0..127
    const int role = w & 1;            // 0=A, 1=B
    const int bsel = (w >> 1) & 1;
    const int j    = w >> 2;           // pair index 0..31
    const int b    = r * 2 + bsel;
    const int T    = 63 - j;           // deep tile of the pair (depth 64-j)

    // item list (<=2): {tile, kt0, kt1, partial(half)}
    int it_tile[2], it_k0[2], it_k1[2], it_half[2], n_items;
    if (role == 0) {                   // A: tile j full + head of T
        it_tile[0] = j;  it_k0[0] = 0; it_k1[0] = j + 1;  it_half[0] = -1;
        it_tile[1] = T;  it_k0[1] = 0; it_k1[1] = 31 - j; it_half[1] = 0;
        n_items = 2;                   // total (j+1)+(31-j) = 32
    } else {                           // B: tail of T (33 k-tiles)
        it_tile[0] = T;  it_k0[0] = 31 - j; it_k1[0] = 64 - j; it_half[0] = 1;
        n_items = 1;
    }

    // loop-invariant LDS byte addresses
    int kaddr[4];   // [s]: K A-frag, image row wk*32+l31, granule (s*2+h)^l7
    #pragma unroll
    for (int s = 0; s < 4; ++s)
        kaddr[s] = (wk * 32 + l31) * 128 + (((s * 2 + h) ^ l7) * 16);
    int vbase[2];   // [t]: V B-frag, row l31 (+dvt*32 via imm), granule (wk*4+t*2+h)^l7
    #pragma unroll
    for (int t = 0; t < 2; ++t)
        vbase[t] = l31 * 128 + (((wk * 4 + t * 2 + h) ^ l7) * 16);

    const int dma_off = wave * 1024 + lane * 8;       // u16; 16B per lane
    const u16x8 ones_u = {0x3F80, 0x3F80, 0x3F80, 0x3F80,
                          0x3F80, 0x3F80, 0x3F80, 0x3F80};
    const bf16x8 ones8 = __builtin_bit_cast(bf16x8, ones_u);
    const float QS = 0.125f * 1.44269504f;            // scale * log2(e)

    const unsigned short* kt_src = wsK + (size_t)b * 64 * 4096;
    const unsigned short* vt_src = wsV + (size_t)b * 64 * 4096;

    for (int it = 0; it < n_items; ++it) {
        const int tt   = it_tile[it];
        const int kt0  = it_k0[it];
        const int kt1  = it_k1[it];
        const int half = it_half[it];
        const int i0   = tt * 64;

        __syncthreads();                 // LDS free from previous item

        f32x16 o_acc[2] = {};  // [dvt]: D[q][dv], col dv=dvt*32+l31, rows q-pattern
        f32x16 lones = {};     // row sums via ones-MFMA (same q rows, every lane)

        if (kt0 < kt1) {
            // Q fragments (B-operand): lane = q row wq*32+l31, k = s*16+h*8+j
            u16x8 qb[4];
            const float* qptr = Q + ((size_t)b * N_SEQ + i0 + wq * 32 + l31) * DIM;
            #pragma unroll
            for (int s = 0; s < 4; ++s) {
                const float* p = qptr + s * 16 + h * 8;
                f32x4 f0 = *reinterpret_cast<const f32x4*>(p);
                f32x4 f1 = *reinterpret_cast<const f32x4*>(p + 4);
                #pragma unroll
                for (int jj = 0; jj < 4; ++jj) {
                    qb[s][jj]     = f2bf(f0[jj] * QS);
                    qb[s][4 + jj] = f2bf(f1[jj] * QS);
                }
            }

            auto dma = [&](int kt, int bufi) {            // 16 KB per k-tile
                const unsigned short* ks = kt_src + (size_t)kt * 4096 + dma_off;
                const unsigned short* vs = vt_src + (size_t)kt * 4096 + dma_off;
                #pragma unroll
                for (int i = 0; i < 2; ++i) {
                    gl_lds16(ks + i * 512, &kbuf[bufi][wave * 1024 + i * 512]);
                    gl_lds16(vs + i * 512, &vbuf[bufi][wave * 1024 + i * 512]);
                }
            };

            auto compute = [&](int kt, const unsigned short* kb, const unsigned short* vb) {
                // S^T quadrant = K(wk-half, row-permuted) * Q^T(wq-half)
                // D: col = q = l31, reg rr = kpos K0[rr]+8h (image perm folded)
                f32x16 st = {};
                #pragma unroll
                for (int s = 0; s < 4; ++s) {
                    bf16x8 kf = ld_frag((const char*)kb + kaddr[s]);
                    st = mfma32(kf, __builtin_bit_cast(bf16x8, qb[s]), st);
                }
                // P = exp2(S^T) (+ causal mask on diagonal tile)
                float pex[16];
                if (kt == tt) {
                    const int qth = wq * 32 + l31 - 8 * h - wk * 32;
                    #pragma unroll
                    for (int rr = 0; rr < 16; ++rr) {
                        const int K0 = (rr & 7) | ((rr & 8) << 1);
                        pex[rr] = fexp2((K0 > qth) ? -3.0e38f : st[rr]);
                    }
                } else {
                    #pragma unroll
                    for (int rr = 0; rr < 16; ++rr)
                        pex[rr] = fexp2(st[rr]);
                }
                // reg order == PV A-layout k order (thanks to K row permutation):
                // A slice t = words u[4t..4t+3], kpos = wk*32 + 16t + 8h + (0..7)
                unsigned int u[8];
                #pragma unroll
                for (int g = 0; g < 4; ++g) {
                    u[2 * g]     = pk2bf(pex[4 * g],     pex[4 * g + 1]);
                    u[2 * g + 1] = pk2bf(pex[4 * g + 2], pex[4 * g + 3]);
                }
                // O += P V ; l += P * ones
                #pragma unroll
                for (int t = 0; t < 2; ++t) {
                    uint4 aw = make_uint4(u[4 * t], u[4 * t + 1], u[4 * t + 2], u[4 * t + 3]);
                    bf16x8 pa = __builtin_bit_cast(bf16x8, aw);
                    #pragma unroll
                    for (int dvt = 0; dvt < 2; ++dvt) {
                        bf16x8 bv = ld_frag((const char*)vb + vbase[t] + dvt * 4096);
                        o_acc[dvt] = mfma32(pa, bv, o_acc[dvt]);
                    }
                    lones = mfma32(pa, ones8, lones);
                }
            };

            dma(kt0, 0);
            int kt = kt0, bufi = 0;
            while (true) {
                // ---- counted-vmcnt double-buffer pipeline (no vmcnt(0) drain) ----
                __builtin_amdgcn_s_barrier();          // all waves done READING buf^1
                __builtin_amdgcn_sched_barrier(0);
                if (kt + 1 < kt1) {
                    dma(kt + 1, bufi ^ 1);             // 4 loads, stay in flight
                    asm volatile("s_waitcnt vmcnt(4)" ::: "memory");  // kt's loads done
                } else {
                    asm volatile("s_waitcnt vmcnt(0)" ::: "memory");  // final tile
                }
                __builtin_amdgcn_sched_barrier(0);
                __builtin_amdgcn_s_barrier();          // kt staged data visible to all
                __builtin_amdgcn_sched_barrier(0);
                compute(kt, kbuf[bufi], vbuf[bufi]);
                if (++kt == kt1) break;
                bufi ^= 1;
            }
        }

        // ---- cross-wk reduction through the freed k-tile LDS (once per item) ----
        __syncthreads();                           // everyone done with kbuf/vbuf
        float* red  = reinterpret_cast<float*>(&kbuf[0][0]);   // 4096 f32 = 16 KB
        float* lred = reinterpret_cast<float*>(&vbuf[0][0]);   // 64 f32 used
        if (wk == 1) {
            #pragma unroll
            for (int rr = 0; rr < 16; ++rr) {
                const int qrow = (rr & 3) + 8 * (rr >> 2) + 4 * h;
                #pragma unroll
                for (int dvt = 0; dvt < 2; ++dvt)
                    red[wq * 2048 + qrow * 64 + dvt * 32 + l31] = o_acc[dvt][rr];
                if (l31 == 0) lred[wq * 32 + qrow] = lones[rr];
            }
        }
        __syncthreads();
        if (wk == 0) {
            if (half < 0) {
                // final: normalize and write O directly
                float* obase = O + ((size_t)b * N_SEQ + i0 + wq * 32) * DIM;
                #pragma unroll
                for (int rr = 0; rr < 16; ++rr) {
                    const int qrow = (rr & 3) + 8 * (rr >> 2) + 4 * h;
                    const float lt = lones[rr] + lred[wq * 32 + qrow];
                    const float inv = 1.0f / lt;
                    #pragma unroll
                    for (int dvt = 0; dvt < 2; ++dvt) {
                        const float val = o_acc[dvt][rr]
                            + red[wq * 2048 + qrow * 64 + dvt * 32 + l31];
                        obase[qrow * DIM + dvt * 32 + l31] = val * inv;
                    }
                }
            } else {
                // raw additive partial -> workspace (zeros if empty range)
                float* po = wsO + (((size_t)(b * 32 + (tt - 32)) * 2 + half) * 4096);
                float* pl = wsL + (((size_t)(b * 32 + (tt - 32)) * 2 + half) * 64);
                #pragma unroll
                for (int rr = 0; rr < 16; ++rr) {
                    const int qrow = (rr & 3) + 8 * (rr >> 2) + 4 * h;
                    const float lt = lones[rr] + lred[wq * 32 + qrow];
                    #pragma unroll
                    for (int dvt = 0; dvt < 2; ++dvt)
                        po[(wq * 32 + qrow) * 64 + dvt * 32 + l31] = o_acc[dvt][rr]
                            + red[wq * 2048 + qrow * 64 + dvt * 32 + l31];
                    if (l31 == 0) pl[wq * 32 + qrow] = lt;
                }
            }
        }
        // next item's top-of-loop __syncthreads() protects kbuf/vbuf reuse
    }
}

// ---- combine split-K partials for tiles 32..63 ----
__global__ __launch_bounds__(256)
void norm_out(const float* __restrict__ wsO, const float* __restrict__ wsL,
              float* __restrict__ O) {
    const int t = 32 + blockIdx.x, b = blockIdx.y;
    const int row = threadIdx.x >> 2;            // 0..63
    const int c0  = (threadIdx.x & 3) * 16;      // 0,16,32,48
    const size_t base = (size_t)(b * 32 + (t - 32)) * 2;
    const float* p0 = wsO + base * 4096 + row * 64 + c0;
    const float* p1 = p0 + 4096;
    const float* l  = wsL + base * 64;
    const float inv = 1.0f / (l[row] + l[64 + row]);
    float* o = O + ((size_t)b * N_SEQ + t * 64 + row) * 64 + c0;
    #pragma unroll
    for (int i = 0; i < 16; i += 4) {
        f32x4 a = *reinterpret_cast<const f32x4*>(p0 + i);
        f32x4 c = *reinterpret_cast<const f32x4*>(p1 + i);
        f32x4 v = (a + c) * inv;
        *reinterpret_cast<f32x4*>(o + i) = v;
    }
}

extern "C" void kernel_launch(void* const* d_in, const int* in_sizes, int n_in,
                              void* d_out, int out_size, void* d_ws, size_t ws_size,
                              hipStream_t stream) {
    const float* q = (const float*)d_in[0];
    const float* k = (const float*)d_in[1];
    const float* v = (const float*)d_in[2];
    // d_in[3] = causal mask, analytic (tril) -- not read.
    float* out = (float*)d_out;

    unsigned short* wsK = (unsigned short*)d_ws;
    unsigned short* wsV = wsK + (size_t)16 * 64 * 4096;        // 8 MB each
    float* wsO = (float*)(wsV + (size_t)16 * 64 * 4096);       // 16.8 MB
    float* wsL = wsO + (size_t)16 * 32 * 2 * 4096;             // 0.26 MB

    prep_kv<<<dim3(64, 16, 2), dim3(256), 0, stream>>>(k, v, wsK, wsV);
    attn_fwd<<<dim3(1024), dim3(256), 0, stream>>>(q, wsK, wsV, out, wsO, wsL);
    norm_out<<<dim3(32, 16), dim3(256), 0, stream>>>(wsO, wsL, out);
}